// Round 1
// baseline (2621.342 us; speedup 1.0000x reference)
//
#include <hip/hip_runtime.h>

#define BN_EPS 1e-5f

// ---------------------------------------------------------------------------
// conv1x1: out[b,co,p] = epilogue( sum_ci w[co,ci] * x[b,ci,p] )
// MODE 0: + bias (p0)      MODE 1: BN(g=p0, bt=p1, m=p2, v=p3) + ReLU
// grid: (ceil(HW/256), C_out/CO_CHUNK, B), block 256
// ---------------------------------------------------------------------------
template<int CO_CHUNK, int MODE>
__global__ __launch_bounds__(256)
void conv1x1_kernel(const float* __restrict__ x, const float* __restrict__ w,
                    const float* __restrict__ p0, const float* __restrict__ p1,
                    const float* __restrict__ p2, const float* __restrict__ p3,
                    float* __restrict__ out, int C_in, int HW)
{
    int p   = blockIdx.x * 256 + threadIdx.x;
    int co0 = blockIdx.y * CO_CHUNK;
    int b   = blockIdx.z;
    if (p >= HW) return;

    float acc[CO_CHUNK];
#pragma unroll
    for (int j = 0; j < CO_CHUNK; ++j) acc[j] = 0.f;

    const float* xp = x + (size_t)b * C_in * HW + p;
    for (int ci = 0; ci < C_in; ++ci) {
        float xv = xp[(size_t)ci * HW];
#pragma unroll
        for (int j = 0; j < CO_CHUNK; ++j)
            acc[j] = fmaf(w[(co0 + j) * C_in + ci], xv, acc[j]);
    }

    int C_out = gridDim.y * CO_CHUNK;
    float* op = out + ((size_t)(b * C_out + co0)) * HW + p;
#pragma unroll
    for (int j = 0; j < CO_CHUNK; ++j) {
        float val;
        if (MODE == 0) {
            val = acc[j] + p0[co0 + j];
        } else {
            float inv = p0[co0 + j] * rsqrtf(p3[co0 + j] + BN_EPS);
            val = acc[j] * inv + (p1[co0 + j] - p2[co0 + j] * inv);
            val = fmaxf(val, 0.f);
        }
        op[(size_t)j * HW] = val;
    }
}

// ---------------------------------------------------------------------------
// conv3x3, pad=1, C_in=64. out[b,co,y,x] = epi( sum_{ci,dy,dx} w*x )
// MODE 0: + bias (p0)      MODE 1: BN(g,bt,m,v)
// grid: (ceil(W/16), ceil(H/16), B * n_chunks), block 256 (16x16 tile)
// ---------------------------------------------------------------------------
template<int CO_CHUNK, int MODE>
__global__ __launch_bounds__(256)
void conv3x3_kernel(const float* __restrict__ x, const float* __restrict__ w,
                    const float* __restrict__ p0, const float* __restrict__ p1,
                    const float* __restrict__ p2, const float* __restrict__ p3,
                    float* __restrict__ out, int H, int W, int n_chunks)
{
    constexpr int CIN = 64, CI_CHUNK = 16;
    __shared__ float lds[CI_CHUNK][18][19];   // +1 pad on row stride

    int tid = threadIdx.x;
    int lx = tid & 15, ly = tid >> 4;
    int x0 = blockIdx.x * 16, y0 = blockIdx.y * 16;
    int b     = blockIdx.z / n_chunks;
    int chunk = blockIdx.z % n_chunks;
    int co0   = chunk * CO_CHUNK;
    int gx = x0 + lx, gy = y0 + ly;

    float acc[CO_CHUNK];
#pragma unroll
    for (int j = 0; j < CO_CHUNK; ++j) acc[j] = 0.f;

    const float* xb = x + (size_t)b * CIN * H * W;

    for (int cc = 0; cc < CIN; cc += CI_CHUNK) {
        // stage CI_CHUNK channels of the (16+2)^2 halo tile
        for (int i = tid; i < CI_CHUNK * 18 * 18; i += 256) {
            int cl = i / 324;
            int r  = i - cl * 324;
            int rr = r / 18;
            int c  = r - rr * 18;
            int yy = y0 + rr - 1, xx = x0 + c - 1;
            float v = 0.f;
            if (yy >= 0 && yy < H && xx >= 0 && xx < W)
                v = xb[((size_t)(cc + cl) * H + yy) * W + xx];
            lds[cl][rr][c] = v;
        }
        __syncthreads();

        for (int cl = 0; cl < CI_CHUNK; ++cl) {
            float iv[9];
#pragma unroll
            for (int dy = 0; dy < 3; ++dy)
#pragma unroll
                for (int dx = 0; dx < 3; ++dx)
                    iv[dy * 3 + dx] = lds[cl][ly + dy][lx + dx];

            const float* wp = w + ((size_t)co0 * CIN + (cc + cl)) * 9;
#pragma unroll
            for (int j = 0; j < CO_CHUNK; ++j) {
                const float* wj = wp + (size_t)j * CIN * 9;
#pragma unroll
                for (int t = 0; t < 9; ++t)
                    acc[j] = fmaf(wj[t], iv[t], acc[j]);
            }
        }
        __syncthreads();
    }

    if (gx < W && gy < H) {
        int C_out = n_chunks * CO_CHUNK;
        float* op = out + ((size_t)(b * C_out + co0) * H + gy) * W + gx;
#pragma unroll
        for (int j = 0; j < CO_CHUNK; ++j) {
            float val;
            if (MODE == 0) {
                val = acc[j] + p0[co0 + j];
            } else {
                float inv = p0[co0 + j] * rsqrtf(p3[co0 + j] + BN_EPS);
                val = acc[j] * inv + (p1[co0 + j] - p2[co0 + j] * inv);
            }
            op[(size_t)j * H * W] = val;
        }
    }
}

// ---------------------------------------------------------------------------
// CARAFE reassembly: dst(b,64,2h,2w) += sum_k softmax_k(logits) * src neighbor
// logits: (b, 100, h, w), channel = k*4 + (y&1)*2 + (x&1), k = i*5+j
// src neighbor: src[b, c, yh+i-2, xw+j-2] (zero outside)
// grid: (ceil(2w/16), ceil(2h/16), B), block 256
// ---------------------------------------------------------------------------
__global__ __launch_bounds__(256)
void carafe_kernel(const float* __restrict__ src, const float* __restrict__ logits,
                   float* __restrict__ dst, int h, int w)
{
    int H = 2 * h, W = 2 * w;
    int x = blockIdx.x * 16 + (threadIdx.x & 15);
    int y = blockIdx.y * 16 + (threadIdx.x >> 4);
    int b = blockIdx.z;
    if (x >= W || y >= H) return;

    int xw = x >> 1, yh = y >> 1;
    int off = (y & 1) * 2 + (x & 1);
    size_t hw = (size_t)h * w;

    const float* lp = logits + ((size_t)(b * 100 + off) * h + yh) * w + xw;
    float l[25];
    float mx = -1e30f;
#pragma unroll
    for (int k = 0; k < 25; ++k) {
        l[k] = lp[(size_t)(4 * k) * hw];
        mx = fmaxf(mx, l[k]);
    }
    float s = 0.f;
#pragma unroll
    for (int k = 0; k < 25; ++k) {
        l[k] = __expf(l[k] - mx);
        s += l[k];
    }
    float invs = 1.f / s;

    int offs[25];
#pragma unroll
    for (int k = 0; k < 25; ++k) {
        int i = k / 5 - 2, j = k % 5 - 2;
        int yy = yh + i, xx = xw + j;
        bool valid = (yy >= 0) && (yy < h) && (xx >= 0) && (xx < w);
        l[k]    = valid ? l[k] * invs : 0.f;
        offs[k] = valid ? (yy * w + xx) : 0;
    }

    const float* sp = src + (size_t)b * 64 * hw;
    float* dp = dst + ((size_t)(b * 64) * H + y) * W + x;
    for (int c = 0; c < 64; ++c) {
        const float* spc = sp + (size_t)c * hw;
        float acc = 0.f;
#pragma unroll
        for (int k = 0; k < 25; ++k)
            acc = fmaf(l[k], spc[offs[k]], acc);
        dp[(size_t)c * H * W] += acc;
    }
}

// ---------------------------------------------------------------------------
extern "C" void kernel_launch(void* const* d_in, const int* in_sizes, int n_in,
                              void* d_out, int out_size, void* d_ws, size_t ws_size,
                              hipStream_t stream)
{
    // inputs (setup_inputs dict order)
    const float* x0      = (const float*)d_in[0];
    const float* lat0_w  = (const float*)d_in[1];
    const float* lat0_b  = (const float*)d_in[2];
    const float* fpn0_w  = (const float*)d_in[3];
    const float* fpn0_b  = (const float*)d_in[4];
    const float* x1      = (const float*)d_in[5];
    const float* lat1_w  = (const float*)d_in[6];
    const float* lat1_b  = (const float*)d_in[7];
    const float* fpn1_w  = (const float*)d_in[8];
    const float* fpn1_b  = (const float*)d_in[9];
    const float* x2      = (const float*)d_in[10];
    const float* lat2_w  = (const float*)d_in[11];
    const float* lat2_b  = (const float*)d_in[12];
    const float* fpn2_w  = (const float*)d_in[13];
    const float* fpn2_b  = (const float*)d_in[14];
    const float* u0_comp_w = (const float*)d_in[15];
    const float* u0_enc_w  = (const float*)d_in[16];
    const float* u0_comp_g  = (const float*)d_in[17];
    const float* u0_comp_bt = (const float*)d_in[18];
    const float* u0_comp_m  = (const float*)d_in[19];
    const float* u0_comp_v  = (const float*)d_in[20];
    const float* u0_enc_g   = (const float*)d_in[21];
    const float* u0_enc_bt  = (const float*)d_in[22];
    const float* u0_enc_m   = (const float*)d_in[23];
    const float* u0_enc_v   = (const float*)d_in[24];
    const float* u1_comp_w = (const float*)d_in[25];
    const float* u1_enc_w  = (const float*)d_in[26];
    const float* u1_comp_g  = (const float*)d_in[27];
    const float* u1_comp_bt = (const float*)d_in[28];
    const float* u1_comp_m  = (const float*)d_in[29];
    const float* u1_comp_v  = (const float*)d_in[30];
    const float* u1_enc_g   = (const float*)d_in[31];
    const float* u1_enc_bt  = (const float*)d_in[32];
    const float* u1_enc_m   = (const float*)d_in[33];
    const float* u1_enc_v   = (const float*)d_in[34];

    float* out = (float*)d_out;
    // output regions: out0 (4,64,96,160), out1 (4,64,48,80), out2 (4,64,24,40)
    const size_t OUT0 = 4ull * 64 * 96 * 160;   // 3,932,160
    const size_t OUT1 = 4ull * 64 * 48 * 80;    //   983,040
    float* out0 = out;
    float* out1 = out + OUT0;
    float* out2 = out + OUT0 + OUT1;

    // workspace: lateral feature maps (fully overwritten every launch)
    float* lat0 = (float*)d_ws;                 // 3,932,160
    float* lat1 = lat0 + OUT0;                  //   983,040
    float* lat2 = lat1 + OUT1;                  //   245,760
    // comp/enc scratch lives in the out0 region (overwritten last by fpn0 conv)
    float* comp = out0;                         // up to   983,040
    float* enc  = out0 + OUT1;                  // up to 1,536,000  (total 2.52M < 3.93M)

    dim3 blk(256);

    // 1) lateral 1x1 convs + bias
    conv1x1_kernel<32, 0><<<dim3(60, 2, 4), blk, 0, stream>>>(
        x0, lat0_w, lat0_b, nullptr, nullptr, nullptr, lat0, 128, 96 * 160);
    conv1x1_kernel<32, 0><<<dim3(15, 2, 4), blk, 0, stream>>>(
        x1, lat1_w, lat1_b, nullptr, nullptr, nullptr, lat1, 256, 48 * 80);
    conv1x1_kernel<32, 0><<<dim3(4, 2, 4), blk, 0, stream>>>(
        x2, lat2_w, lat2_b, nullptr, nullptr, nullptr, lat2, 512, 24 * 40);

    // 2) CARAFE u1: lat1 += carafe(lat2)
    conv1x1_kernel<32, 1><<<dim3(4, 2, 4), blk, 0, stream>>>(
        lat2, u1_comp_w, u1_comp_g, u1_comp_bt, u1_comp_m, u1_comp_v, comp, 64, 24 * 40);
    conv3x3_kernel<25, 1><<<dim3(3, 2, 16), blk, 0, stream>>>(
        comp, u1_enc_w, u1_enc_g, u1_enc_bt, u1_enc_m, u1_enc_v, enc, 24, 40, 4);
    carafe_kernel<<<dim3(5, 3, 4), blk, 0, stream>>>(lat2, enc, lat1, 24, 40);

    // 3) CARAFE u0: lat0 += carafe(lat1)
    conv1x1_kernel<32, 1><<<dim3(15, 2, 4), blk, 0, stream>>>(
        lat1, u0_comp_w, u0_comp_g, u0_comp_bt, u0_comp_m, u0_comp_v, comp, 64, 48 * 80);
    conv3x3_kernel<25, 1><<<dim3(5, 3, 16), blk, 0, stream>>>(
        comp, u0_enc_w, u0_enc_g, u0_enc_bt, u0_enc_m, u0_enc_v, enc, 48, 80, 4);
    carafe_kernel<<<dim3(10, 6, 4), blk, 0, stream>>>(lat1, enc, lat0, 48, 80);

    // 4) output 3x3 convs + bias  (fpn0 LAST — its region held comp/enc scratch)
    conv3x3_kernel<32, 0><<<dim3(5, 3, 8), blk, 0, stream>>>(
        lat1, fpn1_w, fpn1_b, nullptr, nullptr, nullptr, out1, 48, 80, 2);
    conv3x3_kernel<32, 0><<<dim3(3, 2, 8), blk, 0, stream>>>(
        lat2, fpn2_w, fpn2_b, nullptr, nullptr, nullptr, out2, 24, 40, 2);
    conv3x3_kernel<32, 0><<<dim3(10, 6, 8), blk, 0, stream>>>(
        lat0, fpn0_w, fpn0_b, nullptr, nullptr, nullptr, out0, 96, 160, 2);
}

// Round 2
// 1814.060 us; speedup vs baseline: 1.4450x; 1.4450x over previous
//
#include <hip/hip_runtime.h>

#define BN_EPS 1e-5f

// ---------------------------------------------------------------------------
// conv1x1 v2: out[b,co,p] = epilogue( sum_ci w[co,ci] * x[b,ci,p] )
// Compile-time C_IN so every loop fully unrolls / SROA promotes acc to regs
// (v1 had runtime C_in -> acc[] spilled to scratch, 500us per dispatch).
// CO=8 output channels per block (blockIdx.y), PIX pixels per thread.
// Weights staged transposed in LDS: wl[ci][8] -> broadcast float4 reads.
// MODE 0: + bias (p0)      MODE 1: BN(g=p0, bt=p1, m=p2, v=p3) + ReLU
// grid: (ceil(HW/(256*PIX)), 8, B), block 256.  Requires HW % PIX == 0.
// ---------------------------------------------------------------------------
template<int C_IN, int PIX, int MODE>
__global__ __launch_bounds__(256)
void conv1x1_kernel(const float* __restrict__ x, const float* __restrict__ w,
                    const float* __restrict__ p0, const float* __restrict__ p1,
                    const float* __restrict__ p2, const float* __restrict__ p3,
                    float* __restrict__ out, int HW)
{
    constexpr int CO = 8;
    __shared__ float wl[C_IN][CO];

    int tid = threadIdx.x;
    int co0 = blockIdx.y * CO;
    int b   = blockIdx.z;

    // stage weights transposed: wl[ci][j] = w[(co0+j)*C_IN + ci]
    for (int i = tid; i < C_IN * CO; i += 256) {
        int ci = i >> 3, j = i & 7;
        wl[ci][j] = w[(co0 + j) * C_IN + ci];
    }
    __syncthreads();

    int p = (blockIdx.x * 256 + tid) * PIX;
    if (p >= HW) return;

    float acc[CO][PIX];
#pragma unroll
    for (int j = 0; j < CO; ++j)
#pragma unroll
        for (int q = 0; q < PIX; ++q) acc[j][q] = 0.f;

    const float* xp = x + (size_t)b * C_IN * HW + p;

#pragma unroll 8
    for (int ci = 0; ci < C_IN; ++ci) {
        float xv[PIX];
        if (PIX == 4) {
            float4 v = *(const float4*)(xp + (size_t)ci * HW);
            xv[0] = v.x; xv[1] = v.y; xv[2] = v.z; xv[3] = v.w;
        } else if (PIX == 2) {
            float2 v = *(const float2*)(xp + (size_t)ci * HW);
            xv[0] = v.x; xv[1] = v.y;
        } else {
            xv[0] = xp[(size_t)ci * HW];
        }
        float4 wa = *(const float4*)&wl[ci][0];
        float4 wb = *(const float4*)&wl[ci][4];
        float wj[CO] = {wa.x, wa.y, wa.z, wa.w, wb.x, wb.y, wb.z, wb.w};
#pragma unroll
        for (int j = 0; j < CO; ++j)
#pragma unroll
            for (int q = 0; q < PIX; ++q)
                acc[j][q] = fmaf(wj[j], xv[q], acc[j][q]);
    }

    int C_out = gridDim.y * CO;
    float* op = out + ((size_t)(b * C_out + co0)) * HW + p;
#pragma unroll
    for (int j = 0; j < CO; ++j) {
        float scale, shift;
        if (MODE == 0) {
            scale = 1.f; shift = p0[co0 + j];
        } else {
            float inv = p0[co0 + j] * rsqrtf(p3[co0 + j] + BN_EPS);
            scale = inv; shift = p1[co0 + j] - p2[co0 + j] * inv;
        }
        float r[PIX];
#pragma unroll
        for (int q = 0; q < PIX; ++q) {
            r[q] = acc[j][q] * scale + shift;
            if (MODE == 1) r[q] = fmaxf(r[q], 0.f);
        }
        float* od = op + (size_t)j * HW;
        if (PIX == 4)      *(float4*)od = make_float4(r[0], r[1], r[2], r[3]);
        else if (PIX == 2) *(float2*)od = make_float2(r[0], r[1]);
        else               od[0] = r[0];
    }
}

// ---------------------------------------------------------------------------
// conv3x3, pad=1, C_in=64. out[b,co,y,x] = epi( sum_{ci,dy,dx} w*x )
// MODE 0: + bias (p0)      MODE 1: BN(g,bt,m,v)
// grid: (ceil(W/16), ceil(H/16), B * n_chunks), block 256 (16x16 tile)
// ---------------------------------------------------------------------------
template<int CO_CHUNK, int MODE>
__global__ __launch_bounds__(256)
void conv3x3_kernel(const float* __restrict__ x, const float* __restrict__ w,
                    const float* __restrict__ p0, const float* __restrict__ p1,
                    const float* __restrict__ p2, const float* __restrict__ p3,
                    float* __restrict__ out, int H, int W, int n_chunks)
{
    constexpr int CIN = 64, CI_CHUNK = 16;
    __shared__ float lds[CI_CHUNK][18][19];   // +1 pad on row stride

    int tid = threadIdx.x;
    int lx = tid & 15, ly = tid >> 4;
    int x0 = blockIdx.x * 16, y0 = blockIdx.y * 16;
    int b     = blockIdx.z / n_chunks;
    int chunk = blockIdx.z % n_chunks;
    int co0   = chunk * CO_CHUNK;
    int gx = x0 + lx, gy = y0 + ly;

    float acc[CO_CHUNK];
#pragma unroll
    for (int j = 0; j < CO_CHUNK; ++j) acc[j] = 0.f;

    const float* xb = x + (size_t)b * CIN * H * W;

    for (int cc = 0; cc < CIN; cc += CI_CHUNK) {
        for (int i = tid; i < CI_CHUNK * 18 * 18; i += 256) {
            int cl = i / 324;
            int r  = i - cl * 324;
            int rr = r / 18;
            int c  = r - rr * 18;
            int yy = y0 + rr - 1, xx = x0 + c - 1;
            float v = 0.f;
            if (yy >= 0 && yy < H && xx >= 0 && xx < W)
                v = xb[((size_t)(cc + cl) * H + yy) * W + xx];
            lds[cl][rr][c] = v;
        }
        __syncthreads();

        for (int cl = 0; cl < CI_CHUNK; ++cl) {
            float iv[9];
#pragma unroll
            for (int dy = 0; dy < 3; ++dy)
#pragma unroll
                for (int dx = 0; dx < 3; ++dx)
                    iv[dy * 3 + dx] = lds[cl][ly + dy][lx + dx];

            const float* wp = w + ((size_t)co0 * CIN + (cc + cl)) * 9;
#pragma unroll
            for (int j = 0; j < CO_CHUNK; ++j) {
                const float* wj = wp + (size_t)j * CIN * 9;
#pragma unroll
                for (int t = 0; t < 9; ++t)
                    acc[j] = fmaf(wj[t], iv[t], acc[j]);
            }
        }
        __syncthreads();
    }

    if (gx < W && gy < H) {
        int C_out = n_chunks * CO_CHUNK;
        float* op = out + ((size_t)(b * C_out + co0) * H + gy) * W + gx;
#pragma unroll
        for (int j = 0; j < CO_CHUNK; ++j) {
            float val;
            if (MODE == 0) {
                val = acc[j] + p0[co0 + j];
            } else {
                float inv = p0[co0 + j] * rsqrtf(p3[co0 + j] + BN_EPS);
                val = acc[j] * inv + (p1[co0 + j] - p2[co0 + j] * inv);
            }
            op[(size_t)j * H * W] = val;
        }
    }
}

// ---------------------------------------------------------------------------
// CARAFE reassembly: dst(b,64,2h,2w) += sum_k softmax_k(logits) * src neighbor
// logits: (b, 100, h, w), channel = k*4 + (y&1)*2 + (x&1), k = i*5+j
// src neighbor: src[b, c, yh+i-2, xw+j-2] (zero outside)
// grid: (ceil(2w/16), ceil(2h/16), B), block 256
// ---------------------------------------------------------------------------
__global__ __launch_bounds__(256)
void carafe_kernel(const float* __restrict__ src, const float* __restrict__ logits,
                   float* __restrict__ dst, int h, int w)
{
    int H = 2 * h, W = 2 * w;
    int x = blockIdx.x * 16 + (threadIdx.x & 15);
    int y = blockIdx.y * 16 + (threadIdx.x >> 4);
    int b = blockIdx.z;
    if (x >= W || y >= H) return;

    int xw = x >> 1, yh = y >> 1;
    int off = (y & 1) * 2 + (x & 1);
    size_t hw = (size_t)h * w;

    const float* lp = logits + ((size_t)(b * 100 + off) * h + yh) * w + xw;
    float l[25];
    float mx = -1e30f;
#pragma unroll
    for (int k = 0; k < 25; ++k) {
        l[k] = lp[(size_t)(4 * k) * hw];
        mx = fmaxf(mx, l[k]);
    }
    float s = 0.f;
#pragma unroll
    for (int k = 0; k < 25; ++k) {
        l[k] = __expf(l[k] - mx);
        s += l[k];
    }
    float invs = 1.f / s;

    int offs[25];
#pragma unroll
    for (int k = 0; k < 25; ++k) {
        int i = k / 5 - 2, j = k % 5 - 2;
        int yy = yh + i, xx = xw + j;
        bool valid = (yy >= 0) && (yy < h) && (xx >= 0) && (xx < w);
        l[k]    = valid ? l[k] * invs : 0.f;
        offs[k] = valid ? (yy * w + xx) : 0;
    }

    const float* sp = src + (size_t)b * 64 * hw;
    float* dp = dst + ((size_t)(b * 64) * H + y) * W + x;
    for (int c = 0; c < 64; ++c) {
        const float* spc = sp + (size_t)c * hw;
        float acc = 0.f;
#pragma unroll
        for (int k = 0; k < 25; ++k)
            acc = fmaf(l[k], spc[offs[k]], acc);
        dp[(size_t)c * H * W] += acc;
    }
}

// ---------------------------------------------------------------------------
extern "C" void kernel_launch(void* const* d_in, const int* in_sizes, int n_in,
                              void* d_out, int out_size, void* d_ws, size_t ws_size,
                              hipStream_t stream)
{
    const float* x0      = (const float*)d_in[0];
    const float* lat0_w  = (const float*)d_in[1];
    const float* lat0_b  = (const float*)d_in[2];
    const float* fpn0_w  = (const float*)d_in[3];
    const float* fpn0_b  = (const float*)d_in[4];
    const float* x1      = (const float*)d_in[5];
    const float* lat1_w  = (const float*)d_in[6];
    const float* lat1_b  = (const float*)d_in[7];
    const float* fpn1_w  = (const float*)d_in[8];
    const float* fpn1_b  = (const float*)d_in[9];
    const float* x2      = (const float*)d_in[10];
    const float* lat2_w  = (const float*)d_in[11];
    const float* lat2_b  = (const float*)d_in[12];
    const float* fpn2_w  = (const float*)d_in[13];
    const float* fpn2_b  = (const float*)d_in[14];
    const float* u0_comp_w = (const float*)d_in[15];
    const float* u0_enc_w  = (const float*)d_in[16];
    const float* u0_comp_g  = (const float*)d_in[17];
    const float* u0_comp_bt = (const float*)d_in[18];
    const float* u0_comp_m  = (const float*)d_in[19];
    const float* u0_comp_v  = (const float*)d_in[20];
    const float* u0_enc_g   = (const float*)d_in[21];
    const float* u0_enc_bt  = (const float*)d_in[22];
    const float* u0_enc_m   = (const float*)d_in[23];
    const float* u0_enc_v   = (const float*)d_in[24];
    const float* u1_comp_w = (const float*)d_in[25];
    const float* u1_enc_w  = (const float*)d_in[26];
    const float* u1_comp_g  = (const float*)d_in[27];
    const float* u1_comp_bt = (const float*)d_in[28];
    const float* u1_comp_m  = (const float*)d_in[29];
    const float* u1_comp_v  = (const float*)d_in[30];
    const float* u1_enc_g   = (const float*)d_in[31];
    const float* u1_enc_bt  = (const float*)d_in[32];
    const float* u1_enc_m   = (const float*)d_in[33];
    const float* u1_enc_v   = (const float*)d_in[34];

    float* out = (float*)d_out;
    const size_t OUT0 = 4ull * 64 * 96 * 160;   // 3,932,160
    const size_t OUT1 = 4ull * 64 * 48 * 80;    //   983,040
    float* out0 = out;
    float* out1 = out + OUT0;
    float* out2 = out + OUT0 + OUT1;

    float* lat0 = (float*)d_ws;
    float* lat1 = lat0 + OUT0;
    float* lat2 = lat1 + OUT1;
    // comp/enc scratch lives in the out0 region (overwritten last by fpn0 conv)
    float* comp = out0;
    float* enc  = out0 + OUT1;

    dim3 blk(256);

    // 1) lateral 1x1 convs + bias
    conv1x1_kernel<128, 4, 0><<<dim3(15, 8, 4), blk, 0, stream>>>(
        x0, lat0_w, lat0_b, nullptr, nullptr, nullptr, lat0, 96 * 160);
    conv1x1_kernel<256, 2, 0><<<dim3(8, 8, 4), blk, 0, stream>>>(
        x1, lat1_w, lat1_b, nullptr, nullptr, nullptr, lat1, 48 * 80);
    conv1x1_kernel<512, 1, 0><<<dim3(4, 8, 4), blk, 0, stream>>>(
        x2, lat2_w, lat2_b, nullptr, nullptr, nullptr, lat2, 24 * 40);

    // 2) CARAFE u1: lat1 += carafe(lat2)
    conv1x1_kernel<64, 1, 1><<<dim3(4, 8, 4), blk, 0, stream>>>(
        lat2, u1_comp_w, u1_comp_g, u1_comp_bt, u1_comp_m, u1_comp_v, comp, 24 * 40);
    conv3x3_kernel<25, 1><<<dim3(3, 2, 16), blk, 0, stream>>>(
        comp, u1_enc_w, u1_enc_g, u1_enc_bt, u1_enc_m, u1_enc_v, enc, 24, 40, 4);
    carafe_kernel<<<dim3(5, 3, 4), blk, 0, stream>>>(lat2, enc, lat1, 24, 40);

    // 3) CARAFE u0: lat0 += carafe(lat1)
    conv1x1_kernel<64, 1, 1><<<dim3(15, 8, 4), blk, 0, stream>>>(
        lat1, u0_comp_w, u0_comp_g, u0_comp_bt, u0_comp_m, u0_comp_v, comp, 48 * 80);
    conv3x3_kernel<25, 1><<<dim3(5, 3, 16), blk, 0, stream>>>(
        comp, u0_enc_w, u0_enc_g, u0_enc_bt, u0_enc_m, u0_enc_v, enc, 48, 80, 4);
    carafe_kernel<<<dim3(10, 6, 4), blk, 0, stream>>>(lat1, enc, lat0, 48, 80);

    // 4) output 3x3 convs + bias  (fpn0 LAST — its region held comp/enc scratch)
    conv3x3_kernel<32, 0><<<dim3(5, 3, 8), blk, 0, stream>>>(
        lat1, fpn1_w, fpn1_b, nullptr, nullptr, nullptr, out1, 48, 80, 2);
    conv3x3_kernel<32, 0><<<dim3(3, 2, 8), blk, 0, stream>>>(
        lat2, fpn2_w, fpn2_b, nullptr, nullptr, nullptr, out2, 24, 40, 2);
    conv3x3_kernel<32, 0><<<dim3(10, 6, 8), blk, 0, stream>>>(
        lat0, fpn0_w, fpn0_b, nullptr, nullptr, nullptr, out0, 96, 160, 2);
}

// Round 3
// 1078.086 us; speedup vs baseline: 2.4315x; 1.6827x over previous
//
#include <hip/hip_runtime.h>

#define BN_EPS 1e-5f

// ---------------------------------------------------------------------------
// conv1x1: out[b,co,p] = epilogue( sum_ci w[co,ci] * x[b,ci,p] )
// Compile-time C_IN; CO=8 co per block; PIX pixels/thread; weights in LDS.
// MODE 0: + bias (p0)      MODE 1: BN(g=p0, bt=p1, m=p2, v=p3) + ReLU
// grid: (ceil(HW/(256*PIX)), 8, B), block 256.  Requires HW % PIX == 0.
// ---------------------------------------------------------------------------
template<int C_IN, int PIX, int MODE>
__global__ __launch_bounds__(256)
void conv1x1_kernel(const float* __restrict__ x, const float* __restrict__ w,
                    const float* __restrict__ p0, const float* __restrict__ p1,
                    const float* __restrict__ p2, const float* __restrict__ p3,
                    float* __restrict__ out, int HW)
{
    constexpr int CO = 8;
    __shared__ float wl[C_IN][CO];

    int tid = threadIdx.x;
    int co0 = blockIdx.y * CO;
    int b   = blockIdx.z;

    for (int i = tid; i < C_IN * CO; i += 256) {
        int ci = i >> 3, j = i & 7;
        wl[ci][j] = w[(co0 + j) * C_IN + ci];
    }
    __syncthreads();

    int p = (blockIdx.x * 256 + tid) * PIX;
    if (p >= HW) return;

    float acc[CO][PIX];
#pragma unroll
    for (int j = 0; j < CO; ++j)
#pragma unroll
        for (int q = 0; q < PIX; ++q) acc[j][q] = 0.f;

    const float* xp = x + (size_t)b * C_IN * HW + p;

#pragma unroll 8
    for (int ci = 0; ci < C_IN; ++ci) {
        float xv[PIX];
        if (PIX == 4) {
            float4 v = *(const float4*)(xp + (size_t)ci * HW);
            xv[0] = v.x; xv[1] = v.y; xv[2] = v.z; xv[3] = v.w;
        } else if (PIX == 2) {
            float2 v = *(const float2*)(xp + (size_t)ci * HW);
            xv[0] = v.x; xv[1] = v.y;
        } else {
            xv[0] = xp[(size_t)ci * HW];
        }
        float4 wa = *(const float4*)&wl[ci][0];
        float4 wb = *(const float4*)&wl[ci][4];
        float wj[CO] = {wa.x, wa.y, wa.z, wa.w, wb.x, wb.y, wb.z, wb.w};
#pragma unroll
        for (int j = 0; j < CO; ++j)
#pragma unroll
            for (int q = 0; q < PIX; ++q)
                acc[j][q] = fmaf(wj[j], xv[q], acc[j][q]);
    }

    int C_out = gridDim.y * CO;
    float* op = out + ((size_t)(b * C_out + co0)) * HW + p;
#pragma unroll
    for (int j = 0; j < CO; ++j) {
        float scale, shift;
        if (MODE == 0) {
            scale = 1.f; shift = p0[co0 + j];
        } else {
            float inv = p0[co0 + j] * rsqrtf(p3[co0 + j] + BN_EPS);
            scale = inv; shift = p1[co0 + j] - p2[co0 + j] * inv;
        }
        float r[PIX];
#pragma unroll
        for (int q = 0; q < PIX; ++q) {
            r[q] = acc[j][q] * scale + shift;
            if (MODE == 1) r[q] = fmaxf(r[q], 0.f);
        }
        float* od = op + (size_t)j * HW;
        if (PIX == 4)      *(float4*)od = make_float4(r[0], r[1], r[2], r[3]);
        else if (PIX == 2) *(float2*)od = make_float2(r[0], r[1]);
        else               od[0] = r[0];
    }
}

// ---------------------------------------------------------------------------
// conv3x3 v3, pad=1, C_in=64.
// v2 had CO_CHUNK=32: acc[]+iv[] > 36 VGPR -> scratch spill (FETCH 57MB vs
// 16MB ideal). v3: CO_CHUNK=8/10 so acc stays in registers; LDS row stride 24
// (24 mod 32 -> each wave row quad hits disjoint 8-bank groups, free 2-way).
// Weights read via wave-uniform scalar loads (block-uniform address).
// MODE 0: + bias (p0)      MODE 1: BN(g,bt,m,v)
// grid: (ceil(W/16), ceil(H/16), B * n_chunks), block 256 (16x16 tile)
// ---------------------------------------------------------------------------
template<int CO_CHUNK, int MODE>
__global__ __launch_bounds__(256)
void conv3x3_kernel(const float* __restrict__ x, const float* __restrict__ w,
                    const float* __restrict__ p0, const float* __restrict__ p1,
                    const float* __restrict__ p2, const float* __restrict__ p3,
                    float* __restrict__ out, int H, int W, int n_chunks)
{
    constexpr int CIN = 64, CI_CHUNK = 16, RS = 24;  // RS: padded row stride
    __shared__ float lds[CI_CHUNK][18][RS];

    int tid = threadIdx.x;
    int lx = tid & 15, ly = tid >> 4;
    int x0 = blockIdx.x * 16, y0 = blockIdx.y * 16;
    int b     = blockIdx.z / n_chunks;
    int chunk = blockIdx.z % n_chunks;
    int co0   = chunk * CO_CHUNK;
    int gx = x0 + lx, gy = y0 + ly;

    float acc[CO_CHUNK];
#pragma unroll
    for (int j = 0; j < CO_CHUNK; ++j) acc[j] = 0.f;

    const float* xb = x + (size_t)b * CIN * H * W;

    for (int cc = 0; cc < CIN; cc += CI_CHUNK) {
        for (int i = tid; i < CI_CHUNK * 18 * 18; i += 256) {
            int cl = i / 324;
            int r  = i - cl * 324;
            int rr = r / 18;
            int c  = r - rr * 18;
            int yy = y0 + rr - 1, xx = x0 + c - 1;
            float v = 0.f;
            if (yy >= 0 && yy < H && xx >= 0 && xx < W)
                v = xb[((size_t)(cc + cl) * H + yy) * W + xx];
            lds[cl][rr][c] = v;
        }
        __syncthreads();

        for (int cl = 0; cl < CI_CHUNK; ++cl) {
            float iv[9];
#pragma unroll
            for (int dy = 0; dy < 3; ++dy)
#pragma unroll
                for (int dx = 0; dx < 3; ++dx)
                    iv[dy * 3 + dx] = lds[cl][ly + dy][lx + dx];

            const float* wp = w + ((size_t)co0 * CIN + (cc + cl)) * 9;
#pragma unroll
            for (int j = 0; j < CO_CHUNK; ++j) {
                const float* wj = wp + (size_t)j * CIN * 9;
#pragma unroll
                for (int t = 0; t < 9; ++t)
                    acc[j] = fmaf(wj[t], iv[t], acc[j]);
            }
        }
        __syncthreads();
    }

    if (gx < W && gy < H) {
        int C_out = n_chunks * CO_CHUNK;
        float* op = out + ((size_t)(b * C_out + co0) * H + gy) * W + gx;
#pragma unroll
        for (int j = 0; j < CO_CHUNK; ++j) {
            float val;
            if (MODE == 0) {
                val = acc[j] + p0[co0 + j];
            } else {
                float inv = p0[co0 + j] * rsqrtf(p3[co0 + j] + BN_EPS);
                val = acc[j] * inv + (p1[co0 + j] - p2[co0 + j] * inv);
            }
            op[(size_t)j * H * W] = val;
        }
    }
}

// ---------------------------------------------------------------------------
// CARAFE reassembly: dst(b,64,2h,2w) += sum_k softmax_k(logits) * src neighbor
// logits: (b, 100, h, w), channel = k*4 + (y&1)*2 + (x&1), k = i*5+j
// grid: (ceil(2w/16), ceil(2h/16), B), block 256
// ---------------------------------------------------------------------------
__global__ __launch_bounds__(256)
void carafe_kernel(const float* __restrict__ src, const float* __restrict__ logits,
                   float* __restrict__ dst, int h, int w)
{
    int H = 2 * h, W = 2 * w;
    int x = blockIdx.x * 16 + (threadIdx.x & 15);
    int y = blockIdx.y * 16 + (threadIdx.x >> 4);
    int b = blockIdx.z;
    if (x >= W || y >= H) return;

    int xw = x >> 1, yh = y >> 1;
    int off = (y & 1) * 2 + (x & 1);
    size_t hw = (size_t)h * w;

    const float* lp = logits + ((size_t)(b * 100 + off) * h + yh) * w + xw;
    float l[25];
    float mx = -1e30f;
#pragma unroll
    for (int k = 0; k < 25; ++k) {
        l[k] = lp[(size_t)(4 * k) * hw];
        mx = fmaxf(mx, l[k]);
    }
    float s = 0.f;
#pragma unroll
    for (int k = 0; k < 25; ++k) {
        l[k] = __expf(l[k] - mx);
        s += l[k];
    }
    float invs = 1.f / s;

    int offs[25];
#pragma unroll
    for (int k = 0; k < 25; ++k) {
        int i = k / 5 - 2, j = k % 5 - 2;
        int yy = yh + i, xx = xw + j;
        bool valid = (yy >= 0) && (yy < h) && (xx >= 0) && (xx < w);
        l[k]    = valid ? l[k] * invs : 0.f;
        offs[k] = valid ? (yy * w + xx) : 0;
    }

    const float* sp = src + (size_t)b * 64 * hw;
    float* dp = dst + ((size_t)(b * 64) * H + y) * W + x;
    for (int c = 0; c < 64; ++c) {
        const float* spc = sp + (size_t)c * hw;
        float acc = 0.f;
#pragma unroll
        for (int k = 0; k < 25; ++k)
            acc = fmaf(l[k], spc[offs[k]], acc);
        dp[(size_t)c * H * W] += acc;
    }
}

// ---------------------------------------------------------------------------
extern "C" void kernel_launch(void* const* d_in, const int* in_sizes, int n_in,
                              void* d_out, int out_size, void* d_ws, size_t ws_size,
                              hipStream_t stream)
{
    const float* x0      = (const float*)d_in[0];
    const float* lat0_w  = (const float*)d_in[1];
    const float* lat0_b  = (const float*)d_in[2];
    const float* fpn0_w  = (const float*)d_in[3];
    const float* fpn0_b  = (const float*)d_in[4];
    const float* x1      = (const float*)d_in[5];
    const float* lat1_w  = (const float*)d_in[6];
    const float* lat1_b  = (const float*)d_in[7];
    const float* fpn1_w  = (const float*)d_in[8];
    const float* fpn1_b  = (const float*)d_in[9];
    const float* x2      = (const float*)d_in[10];
    const float* lat2_w  = (const float*)d_in[11];
    const float* lat2_b  = (const float*)d_in[12];
    const float* fpn2_w  = (const float*)d_in[13];
    const float* fpn2_b  = (const float*)d_in[14];
    const float* u0_comp_w = (const float*)d_in[15];
    const float* u0_enc_w  = (const float*)d_in[16];
    const float* u0_comp_g  = (const float*)d_in[17];
    const float* u0_comp_bt = (const float*)d_in[18];
    const float* u0_comp_m  = (const float*)d_in[19];
    const float* u0_comp_v  = (const float*)d_in[20];
    const float* u0_enc_g   = (const float*)d_in[21];
    const float* u0_enc_bt  = (const float*)d_in[22];
    const float* u0_enc_m   = (const float*)d_in[23];
    const float* u0_enc_v   = (const float*)d_in[24];
    const float* u1_comp_w = (const float*)d_in[25];
    const float* u1_enc_w  = (const float*)d_in[26];
    const float* u1_comp_g  = (const float*)d_in[27];
    const float* u1_comp_bt = (const float*)d_in[28];
    const float* u1_comp_m  = (const float*)d_in[29];
    const float* u1_comp_v  = (const float*)d_in[30];
    const float* u1_enc_g   = (const float*)d_in[31];
    const float* u1_enc_bt  = (const float*)d_in[32];
    const float* u1_enc_m   = (const float*)d_in[33];
    const float* u1_enc_v   = (const float*)d_in[34];

    float* out = (float*)d_out;
    const size_t OUT0 = 4ull * 64 * 96 * 160;   // 3,932,160
    const size_t OUT1 = 4ull * 64 * 48 * 80;    //   983,040
    float* out0 = out;
    float* out1 = out + OUT0;
    float* out2 = out + OUT0 + OUT1;

    float* lat0 = (float*)d_ws;
    float* lat1 = lat0 + OUT0;
    float* lat2 = lat1 + OUT1;
    // comp/enc scratch lives in the out0 region (overwritten last by fpn0 conv)
    float* comp = out0;
    float* enc  = out0 + OUT1;

    dim3 blk(256);

    // 1) lateral 1x1 convs + bias
    conv1x1_kernel<128, 4, 0><<<dim3(15, 8, 4), blk, 0, stream>>>(
        x0, lat0_w, lat0_b, nullptr, nullptr, nullptr, lat0, 96 * 160);
    conv1x1_kernel<256, 2, 0><<<dim3(8, 8, 4), blk, 0, stream>>>(
        x1, lat1_w, lat1_b, nullptr, nullptr, nullptr, lat1, 48 * 80);
    conv1x1_kernel<512, 1, 0><<<dim3(4, 8, 4), blk, 0, stream>>>(
        x2, lat2_w, lat2_b, nullptr, nullptr, nullptr, lat2, 24 * 40);

    // 2) CARAFE u1: lat1 += carafe(lat2)
    conv1x1_kernel<64, 1, 1><<<dim3(4, 8, 4), blk, 0, stream>>>(
        lat2, u1_comp_w, u1_comp_g, u1_comp_bt, u1_comp_m, u1_comp_v, comp, 24 * 40);
    conv3x3_kernel<10, 1><<<dim3(3, 2, 40), blk, 0, stream>>>(
        comp, u1_enc_w, u1_enc_g, u1_enc_bt, u1_enc_m, u1_enc_v, enc, 24, 40, 10);
    carafe_kernel<<<dim3(5, 3, 4), blk, 0, stream>>>(lat2, enc, lat1, 24, 40);

    // 3) CARAFE u0: lat0 += carafe(lat1)
    conv1x1_kernel<64, 1, 1><<<dim3(15, 8, 4), blk, 0, stream>>>(
        lat1, u0_comp_w, u0_comp_g, u0_comp_bt, u0_comp_m, u0_comp_v, comp, 48 * 80);
    conv3x3_kernel<10, 1><<<dim3(5, 3, 40), blk, 0, stream>>>(
        comp, u0_enc_w, u0_enc_g, u0_enc_bt, u0_enc_m, u0_enc_v, enc, 48, 80, 10);
    carafe_kernel<<<dim3(10, 6, 4), blk, 0, stream>>>(lat1, enc, lat0, 48, 80);

    // 4) output 3x3 convs + bias  (fpn0 LAST — its region held comp/enc scratch)
    conv3x3_kernel<8, 0><<<dim3(5, 3, 32), blk, 0, stream>>>(
        lat1, fpn1_w, fpn1_b, nullptr, nullptr, nullptr, out1, 48, 80, 8);
    conv3x3_kernel<8, 0><<<dim3(3, 2, 32), blk, 0, stream>>>(
        lat2, fpn2_w, fpn2_b, nullptr, nullptr, nullptr, out2, 24, 40, 8);
    conv3x3_kernel<8, 0><<<dim3(10, 6, 32), blk, 0, stream>>>(
        lat0, fpn0_w, fpn0_b, nullptr, nullptr, nullptr, out0, 96, 160, 8);
}

// Round 4
// 785.414 us; speedup vs baseline: 3.3375x; 1.3726x over previous
//
#include <hip/hip_runtime.h>

#define BN_EPS 1e-5f

// ---------------------------------------------------------------------------
// conv1x1: out[b,co,p] = epilogue( sum_ci w[co,ci] * x[b,ci,p] )
// Compile-time C_IN; CO=8 co per block; PIX pixels/thread; weights in LDS.
// MODE 0: + bias (p0)      MODE 1: BN(g=p0, bt=p1, m=p2, v=p3) + ReLU
// grid: (ceil(HW/(256*PIX)), 8, B), block 256.  Requires HW % PIX == 0.
// ---------------------------------------------------------------------------
template<int C_IN, int PIX, int MODE>
__global__ __launch_bounds__(256)
void conv1x1_kernel(const float* __restrict__ x, const float* __restrict__ w,
                    const float* __restrict__ p0, const float* __restrict__ p1,
                    const float* __restrict__ p2, const float* __restrict__ p3,
                    float* __restrict__ out, int HW)
{
    constexpr int CO = 8;
    __shared__ float wl[C_IN][CO];

    int tid = threadIdx.x;
    int co0 = blockIdx.y * CO;
    int b   = blockIdx.z;

    for (int i = tid; i < C_IN * CO; i += 256) {
        int ci = i >> 3, j = i & 7;
        wl[ci][j] = w[(co0 + j) * C_IN + ci];
    }
    __syncthreads();

    int p = (blockIdx.x * 256 + tid) * PIX;
    if (p >= HW) return;

    float acc[CO][PIX];
#pragma unroll
    for (int j = 0; j < CO; ++j)
#pragma unroll
        for (int q = 0; q < PIX; ++q) acc[j][q] = 0.f;

    const float* xp = x + (size_t)b * C_IN * HW + p;

#pragma unroll 8
    for (int ci = 0; ci < C_IN; ++ci) {
        float xv[PIX];
        if (PIX == 4) {
            float4 v = *(const float4*)(xp + (size_t)ci * HW);
            xv[0] = v.x; xv[1] = v.y; xv[2] = v.z; xv[3] = v.w;
        } else if (PIX == 2) {
            float2 v = *(const float2*)(xp + (size_t)ci * HW);
            xv[0] = v.x; xv[1] = v.y;
        } else {
            xv[0] = xp[(size_t)ci * HW];
        }
        float4 wa = *(const float4*)&wl[ci][0];
        float4 wb = *(const float4*)&wl[ci][4];
        float wj[CO] = {wa.x, wa.y, wa.z, wa.w, wb.x, wb.y, wb.z, wb.w};
#pragma unroll
        for (int j = 0; j < CO; ++j)
#pragma unroll
            for (int q = 0; q < PIX; ++q)
                acc[j][q] = fmaf(wj[j], xv[q], acc[j][q]);
    }

    int C_out = gridDim.y * CO;
    float* op = out + ((size_t)(b * C_out + co0)) * HW + p;
#pragma unroll
    for (int j = 0; j < CO; ++j) {
        float scale, shift;
        if (MODE == 0) {
            scale = 1.f; shift = p0[co0 + j];
        } else {
            float inv = p0[co0 + j] * rsqrtf(p3[co0 + j] + BN_EPS);
            scale = inv; shift = p1[co0 + j] - p2[co0 + j] * inv;
        }
        float r[PIX];
#pragma unroll
        for (int q = 0; q < PIX; ++q) {
            r[q] = acc[j][q] * scale + shift;
            if (MODE == 1) r[q] = fmaxf(r[q], 0.f);
        }
        float* od = op + (size_t)j * HW;
        if (PIX == 4)      *(float4*)od = make_float4(r[0], r[1], r[2], r[3]);
        else if (PIX == 2) *(float2*)od = make_float2(r[0], r[1]);
        else               od[0] = r[0];
    }
}

// ---------------------------------------------------------------------------
// conv3x3, pad=1, C_in=64.  CO_CHUNK small so acc stays in registers.
// LDS row stride 24 (free 2-way bank aliasing only).
// MODE 0: + bias (p0)      MODE 1: BN(g,bt,m,v)
// grid: (ceil(W/16), ceil(H/16), B * n_chunks), block 256 (16x16 tile)
// ---------------------------------------------------------------------------
template<int CO_CHUNK, int MODE>
__global__ __launch_bounds__(256)
void conv3x3_kernel(const float* __restrict__ x, const float* __restrict__ w,
                    const float* __restrict__ p0, const float* __restrict__ p1,
                    const float* __restrict__ p2, const float* __restrict__ p3,
                    float* __restrict__ out, int H, int W, int n_chunks)
{
    constexpr int CIN = 64, CI_CHUNK = 16, RS = 24;
    __shared__ float lds[CI_CHUNK][18][RS];

    int tid = threadIdx.x;
    int lx = tid & 15, ly = tid >> 4;
    int x0 = blockIdx.x * 16, y0 = blockIdx.y * 16;
    int b     = blockIdx.z / n_chunks;
    int chunk = blockIdx.z % n_chunks;
    int co0   = chunk * CO_CHUNK;
    int gx = x0 + lx, gy = y0 + ly;

    float acc[CO_CHUNK];
#pragma unroll
    for (int j = 0; j < CO_CHUNK; ++j) acc[j] = 0.f;

    const float* xb = x + (size_t)b * CIN * H * W;

    for (int cc = 0; cc < CIN; cc += CI_CHUNK) {
        for (int i = tid; i < CI_CHUNK * 18 * 18; i += 256) {
            int cl = i / 324;
            int r  = i - cl * 324;
            int rr = r / 18;
            int c  = r - rr * 18;
            int yy = y0 + rr - 1, xx = x0 + c - 1;
            float v = 0.f;
            if (yy >= 0 && yy < H && xx >= 0 && xx < W)
                v = xb[((size_t)(cc + cl) * H + yy) * W + xx];
            lds[cl][rr][c] = v;
        }
        __syncthreads();

        for (int cl = 0; cl < CI_CHUNK; ++cl) {
            float iv[9];
#pragma unroll
            for (int dy = 0; dy < 3; ++dy)
#pragma unroll
                for (int dx = 0; dx < 3; ++dx)
                    iv[dy * 3 + dx] = lds[cl][ly + dy][lx + dx];

            const float* wp = w + ((size_t)co0 * CIN + (cc + cl)) * 9;
#pragma unroll
            for (int j = 0; j < CO_CHUNK; ++j) {
                const float* wj = wp + (size_t)j * CIN * 9;
#pragma unroll
                for (int t = 0; t < 9; ++t)
                    acc[j] = fmaf(wj[t], iv[t], acc[j]);
            }
        }
        __syncthreads();
    }

    if (gx < W && gy < H) {
        int C_out = n_chunks * CO_CHUNK;
        float* op = out + ((size_t)(b * C_out + co0) * H + gy) * W + gx;
#pragma unroll
        for (int j = 0; j < CO_CHUNK; ++j) {
            float val;
            if (MODE == 0) {
                val = acc[j] + p0[co0 + j];
            } else {
                float inv = p0[co0 + j] * rsqrtf(p3[co0 + j] + BN_EPS);
                val = acc[j] * inv + (p1[co0 + j] - p2[co0 + j] * inv);
            }
            op[(size_t)j * H * W] = val;
        }
    }
}

// ---------------------------------------------------------------------------
// CARAFE v2: dst(b,64,2h,2w) += sum_k softmax_k(logits) * src[.., yh+i-2, xw+j-2]
// v1 failure: offs[25] spilled to scratch (VGPR=44 < live set) -> 300-cyc
// dependent chains; u1 grid only 60 blocks -> 2.3% occupancy.
// v2: no offs array — per-k offset = off0 + (valid_k ? i*w+j : 0) with i*w+j a
// wave-uniform SGPR constant and validity a 25-bit mask; invalid taps load
// off0 (in-bounds) with weight zeroed. k-outer / channel-inner loop, acc[CPG].
// Channels split across blocks: grid (ceil(2w/16), ceil(2h/16), B * (64/CPG)).
// ---------------------------------------------------------------------------
template<int CPG>
__global__ __launch_bounds__(256, 4)
void carafe_kernel(const float* __restrict__ src, const float* __restrict__ logits,
                   float* __restrict__ dst, int h, int w)
{
    constexpr int NCG = 64 / CPG;
    int H = 2 * h, W = 2 * w;
    int x = blockIdx.x * 16 + (threadIdx.x & 15);
    int y = blockIdx.y * 16 + (threadIdx.x >> 4);
    int b  = blockIdx.z / NCG;
    int cg = blockIdx.z % NCG;
    if (x >= W || y >= H) return;

    int xw = x >> 1, yh = y >> 1;
    int par = (y & 1) * 2 + (x & 1);
    size_t hw = (size_t)h * w;

    const float* lp = logits + ((size_t)(b * 100 + par) * h + yh) * w + xw;
    float l[25];
    float mx = -1e30f;
#pragma unroll
    for (int k = 0; k < 25; ++k) {
        l[k] = lp[(size_t)(4 * k) * hw];
        mx = fmaxf(mx, l[k]);
    }
    float s = 0.f;
#pragma unroll
    for (int k = 0; k < 25; ++k) {
        l[k] = __expf(l[k] - mx);
        s += l[k];
    }
    float invs = 1.f / s;

    unsigned vmask = 0;
#pragma unroll
    for (int k = 0; k < 25; ++k) {
        int i = k / 5 - 2, j = k % 5 - 2;
        bool valid = (yh + i >= 0) && (yh + i < h) && (xw + j >= 0) && (xw + j < w);
        if (valid) vmask |= (1u << k);
        l[k] = valid ? l[k] * invs : 0.f;
    }

    int off0 = yh * w + xw;
    const float* sp = src + ((size_t)(b * 64 + cg * CPG)) * hw;

    float acc[CPG];
#pragma unroll
    for (int c = 0; c < CPG; ++c) acc[c] = 0.f;

#pragma unroll
    for (int k = 0; k < 25; ++k) {
        int i = k / 5 - 2, j = k % 5 - 2;
        int cst = i * w + j;                        // SGPR (w uniform, i,j literal)
        int offk = off0 + (((vmask >> k) & 1u) ? cst : 0);
        const float* spk = sp + offk;
        float wk = l[k];
#pragma unroll
        for (int c = 0; c < CPG; ++c)
            acc[c] = fmaf(wk, spk[(size_t)c * hw], acc[c]);
    }

    float* dp = dst + (((size_t)(b * 64 + cg * CPG)) * H + y) * W + x;
#pragma unroll
    for (int c = 0; c < CPG; ++c)
        dp[(size_t)c * H * W] += acc[c];
}

// ---------------------------------------------------------------------------
extern "C" void kernel_launch(void* const* d_in, const int* in_sizes, int n_in,
                              void* d_out, int out_size, void* d_ws, size_t ws_size,
                              hipStream_t stream)
{
    const float* x0      = (const float*)d_in[0];
    const float* lat0_w  = (const float*)d_in[1];
    const float* lat0_b  = (const float*)d_in[2];
    const float* fpn0_w  = (const float*)d_in[3];
    const float* fpn0_b  = (const float*)d_in[4];
    const float* x1      = (const float*)d_in[5];
    const float* lat1_w  = (const float*)d_in[6];
    const float* lat1_b  = (const float*)d_in[7];
    const float* fpn1_w  = (const float*)d_in[8];
    const float* fpn1_b  = (const float*)d_in[9];
    const float* x2      = (const float*)d_in[10];
    const float* lat2_w  = (const float*)d_in[11];
    const float* lat2_b  = (const float*)d_in[12];
    const float* fpn2_w  = (const float*)d_in[13];
    const float* fpn2_b  = (const float*)d_in[14];
    const float* u0_comp_w = (const float*)d_in[15];
    const float* u0_enc_w  = (const float*)d_in[16];
    const float* u0_comp_g  = (const float*)d_in[17];
    const float* u0_comp_bt = (const float*)d_in[18];
    const float* u0_comp_m  = (const float*)d_in[19];
    const float* u0_comp_v  = (const float*)d_in[20];
    const float* u0_enc_g   = (const float*)d_in[21];
    const float* u0_enc_bt  = (const float*)d_in[22];
    const float* u0_enc_m   = (const float*)d_in[23];
    const float* u0_enc_v   = (const float*)d_in[24];
    const float* u1_comp_w = (const float*)d_in[25];
    const float* u1_enc_w  = (const float*)d_in[26];
    const float* u1_comp_g  = (const float*)d_in[27];
    const float* u1_comp_bt = (const float*)d_in[28];
    const float* u1_comp_m  = (const float*)d_in[29];
    const float* u1_comp_v  = (const float*)d_in[30];
    const float* u1_enc_g   = (const float*)d_in[31];
    const float* u1_enc_bt  = (const float*)d_in[32];
    const float* u1_enc_m   = (const float*)d_in[33];
    const float* u1_enc_v   = (const float*)d_in[34];

    float* out = (float*)d_out;
    const size_t OUT0 = 4ull * 64 * 96 * 160;   // 3,932,160
    const size_t OUT1 = 4ull * 64 * 48 * 80;    //   983,040
    float* out0 = out;
    float* out1 = out + OUT0;
    float* out2 = out + OUT0 + OUT1;

    float* lat0 = (float*)d_ws;
    float* lat1 = lat0 + OUT0;
    float* lat2 = lat1 + OUT1;
    // comp/enc scratch lives in the out0 region (overwritten last by fpn0 conv)
    float* comp = out0;
    float* enc  = out0 + OUT1;

    dim3 blk(256);

    // 1) lateral 1x1 convs + bias
    conv1x1_kernel<128, 4, 0><<<dim3(15, 8, 4), blk, 0, stream>>>(
        x0, lat0_w, lat0_b, nullptr, nullptr, nullptr, lat0, 96 * 160);
    conv1x1_kernel<256, 2, 0><<<dim3(8, 8, 4), blk, 0, stream>>>(
        x1, lat1_w, lat1_b, nullptr, nullptr, nullptr, lat1, 48 * 80);
    conv1x1_kernel<512, 1, 0><<<dim3(4, 8, 4), blk, 0, stream>>>(
        x2, lat2_w, lat2_b, nullptr, nullptr, nullptr, lat2, 24 * 40);

    // 2) CARAFE u1: lat1 += carafe(lat2)
    conv1x1_kernel<64, 1, 1><<<dim3(4, 8, 4), blk, 0, stream>>>(
        lat2, u1_comp_w, u1_comp_g, u1_comp_bt, u1_comp_m, u1_comp_v, comp, 24 * 40);
    conv3x3_kernel<10, 1><<<dim3(3, 2, 40), blk, 0, stream>>>(
        comp, u1_enc_w, u1_enc_g, u1_enc_bt, u1_enc_m, u1_enc_v, enc, 24, 40, 10);
    carafe_kernel<16><<<dim3(5, 3, 16), blk, 0, stream>>>(lat2, enc, lat1, 24, 40);

    // 3) CARAFE u0: lat0 += carafe(lat1)
    conv1x1_kernel<64, 1, 1><<<dim3(15, 8, 4), blk, 0, stream>>>(
        lat1, u0_comp_w, u0_comp_g, u0_comp_bt, u0_comp_m, u0_comp_v, comp, 48 * 80);
    conv3x3_kernel<10, 1><<<dim3(5, 3, 40), blk, 0, stream>>>(
        comp, u0_enc_w, u0_enc_g, u0_enc_bt, u0_enc_m, u0_enc_v, enc, 48, 80, 10);
    carafe_kernel<16><<<dim3(10, 6, 16), blk, 0, stream>>>(lat1, enc, lat0, 48, 80);

    // 4) output 3x3 convs + bias  (fpn0 LAST — its region held comp/enc scratch)
    conv3x3_kernel<8, 0><<<dim3(5, 3, 32), blk, 0, stream>>>(
        lat1, fpn1_w, fpn1_b, nullptr, nullptr, nullptr, out1, 48, 80, 8);
    conv3x3_kernel<8, 0><<<dim3(3, 2, 32), blk, 0, stream>>>(
        lat2, fpn2_w, fpn2_b, nullptr, nullptr, nullptr, out2, 24, 40, 8);
    conv3x3_kernel<8, 0><<<dim3(10, 6, 32), blk, 0, stream>>>(
        lat0, fpn0_w, fpn0_b, nullptr, nullptr, nullptr, out0, 96, 160, 8);
}